// Round 1
// baseline (419.667 us; speedup 1.0000x reference)
//
#include <hip/hip_runtime.h>
#include <math.h>

#define N 20000
#define F 128
#define C1 256   // HEADS*HIDDEN
#define HEADS 8
#define HID 32
#define NC 40
#define NEG 0.2f

// ---- edge dtype detection: int64 little-endian => high words of first values are 0
__device__ __forceinline__ int edge_stride(const int* ei) {
    return (ei[1] == 0 && ei[3] == 0 && ei[5] == 0 && ei[7] == 0 && ei[9] == 0) ? 2 : 1;
}

__device__ __forceinline__ float lrelu(float v) { return v > 0.f ? v : NEG * v; }

// ---- K1: h1 = x @ W1 ; as1/ad1 = per-head projections. 16 rows per block.
__global__ __launch_bounds__(256) void k_gemm1(
    const float* __restrict__ x, const float* __restrict__ W1,
    const float* __restrict__ a1s, const float* __restrict__ a1d,
    float* __restrict__ h1, float* __restrict__ as1, float* __restrict__ ad1)
{
    const int t = threadIdx.x;               // output column 0..255
    const int row0 = blockIdx.x * 16;
    float acc[16];
#pragma unroll
    for (int r = 0; r < 16; r++) acc[r] = 0.f;

    for (int k = 0; k < F; k += 4) {
        const float w0 = W1[(k + 0) * C1 + t];
        const float w1 = W1[(k + 1) * C1 + t];
        const float w2 = W1[(k + 2) * C1 + t];
        const float w3 = W1[(k + 3) * C1 + t];
#pragma unroll
        for (int r = 0; r < 16; r++) {
            const float4 xv = *reinterpret_cast<const float4*>(&x[(row0 + r) * F + k]);
            acc[r] = fmaf(xv.x, w0, acc[r]);
            acc[r] = fmaf(xv.y, w1, acc[r]);
            acc[r] = fmaf(xv.z, w2, acc[r]);
            acc[r] = fmaf(xv.w, w3, acc[r]);
        }
    }

    const int head = t >> 5, c = t & 31;
    const float asv = a1s[head * HID + c];
    const float adv = a1d[head * HID + c];
#pragma unroll
    for (int r = 0; r < 16; r++) {
        const float hv = acc[r];
        h1[(row0 + r) * C1 + t] = hv;
        float ps = hv * asv, pd = hv * adv;
#pragma unroll
        for (int off = 16; off >= 1; off >>= 1) {
            ps += __shfl_down(ps, off, 32);
            pd += __shfl_down(pd, off, 32);
        }
        if (c == 0) {
            as1[(row0 + r) * HEADS + head] = ps;
            ad1[(row0 + r) * HEADS + head] = pd;
        }
    }
}

// ---- K2: degree count (incl. self loops)
__global__ void k_count(const int* __restrict__ ei, int E, int* __restrict__ deg)
{
    const int i = blockIdx.x * blockDim.x + threadIdx.x;
    const int ET = E + N;
    if (i >= ET) return;
    const int st = edge_stride(ei);
    const int d = (i < E) ? ei[(size_t)st * (E + i)] : (i - E);
    atomicAdd(&deg[d], 1);
}

// ---- K3: exclusive scan over deg -> rowptr (single block)
__global__ void k_scan(const int* __restrict__ deg, int* __restrict__ rowptr)
{
    __shared__ int sdata[1024];
    __shared__ int s_run;
    const int tid = threadIdx.x;
    if (tid == 0) { s_run = 0; rowptr[0] = 0; }
    __syncthreads();
    for (int base = 0; base < N; base += 1024) {
        const int i = base + tid;
        int v = (i < N) ? deg[i] : 0;
        sdata[tid] = v;
        __syncthreads();
        for (int off = 1; off < 1024; off <<= 1) {
            const int tmp = (tid >= off) ? sdata[tid - off] : 0;
            __syncthreads();
            sdata[tid] += tmp;
            __syncthreads();
        }
        const int run = s_run;
        if (i < N) rowptr[i + 1] = run + sdata[tid];
        __syncthreads();
        if (tid == 0) s_run = run + sdata[1023];
        __syncthreads();
    }
}

// ---- K3b: cursor = rowptr copy
__global__ void k_cursor(const int* __restrict__ rowptr, int* __restrict__ cursor)
{
    const int i = blockIdx.x * blockDim.x + threadIdx.x;
    if (i < N) cursor[i] = rowptr[i];
}

// ---- K4: scatter edge sources into CSR slots
__global__ void k_fill(const int* __restrict__ ei, int E,
                       int* __restrict__ cursor, int* __restrict__ csr)
{
    const int i = blockIdx.x * blockDim.x + threadIdx.x;
    const int ET = E + N;
    if (i >= ET) return;
    const int st = edge_stride(ei);
    int s, d;
    if (i < E) { s = ei[(size_t)st * i]; d = ei[(size_t)st * (E + i)]; }
    else       { s = i - E; d = i - E; }
    const int slot = atomicAdd(&cursor[d], 1);
    csr[slot] = s;
}

// ---- K5: layer-1 softmax aggregation + bias + ELU. One block (256 thr) per node.
__global__ __launch_bounds__(256) void k_agg1(
    const int* __restrict__ rowptr, const int* __restrict__ csr,
    const float* __restrict__ h1, const float* __restrict__ as1,
    const float* __restrict__ ad1, const float* __restrict__ b1,
    float* __restrict__ h1p)
{
    const int n = blockIdx.x;
    const int t = threadIdx.x;
    const int head = t >> 5;
    const float adv = ad1[n * HEADS + head];
    const int beg = rowptr[n], end = rowptr[n + 1];
    float acc = 0.f, accw = 0.f;
    int e = beg;
    for (; e + 3 < end; e += 4) {
        const int s0 = csr[e], s1 = csr[e + 1], s2 = csr[e + 2], s3 = csr[e + 3];
        const float w0 = __expf(lrelu(as1[s0 * HEADS + head] + adv));
        const float w1 = __expf(lrelu(as1[s1 * HEADS + head] + adv));
        const float w2 = __expf(lrelu(as1[s2 * HEADS + head] + adv));
        const float w3 = __expf(lrelu(as1[s3 * HEADS + head] + adv));
        const float h0 = h1[(size_t)s0 * C1 + t];
        const float h1v = h1[(size_t)s1 * C1 + t];
        const float h2v = h1[(size_t)s2 * C1 + t];
        const float h3 = h1[(size_t)s3 * C1 + t];
        accw += (w0 + w1) + (w2 + w3);
        acc = fmaf(w0, h0, acc);
        acc = fmaf(w1, h1v, acc);
        acc = fmaf(w2, h2v, acc);
        acc = fmaf(w3, h3, acc);
    }
    for (; e < end; e++) {
        const int s = csr[e];
        const float w = __expf(lrelu(as1[s * HEADS + head] + adv));
        accw += w;
        acc = fmaf(w, h1[(size_t)s * C1 + t], acc);
    }
    float o = acc / accw + b1[t];
    h1p[(size_t)n * C1 + t] = (o > 0.f) ? o : (__expf(o) - 1.f);
}

// ---- K6: h2 = h1p @ W2 ; as2/ad2 projections. One wave per 4 nodes.
__global__ __launch_bounds__(256) void k_gemm2(
    const float* __restrict__ h1p, const float* __restrict__ W2,
    const float* __restrict__ a2s, const float* __restrict__ a2d,
    float* __restrict__ h2, float* __restrict__ as2, float* __restrict__ ad2)
{
    const int lane = threadIdx.x & 63;
    const int wid = (blockIdx.x * blockDim.x + threadIdx.x) >> 6;  // 0..4999
    const int n0 = wid * 4;
    const int c = lane;
    const int cc = (c < NC) ? c : (NC - 1);
    float acc0 = 0.f, acc1 = 0.f, acc2 = 0.f, acc3 = 0.f;
    for (int k = 0; k < C1; k += 4) {
        const float w0 = W2[(k + 0) * NC + cc];
        const float w1 = W2[(k + 1) * NC + cc];
        const float w2 = W2[(k + 2) * NC + cc];
        const float w3 = W2[(k + 3) * NC + cc];
        const float4 x0 = *reinterpret_cast<const float4*>(&h1p[(size_t)(n0 + 0) * C1 + k]);
        const float4 x1 = *reinterpret_cast<const float4*>(&h1p[(size_t)(n0 + 1) * C1 + k]);
        const float4 x2 = *reinterpret_cast<const float4*>(&h1p[(size_t)(n0 + 2) * C1 + k]);
        const float4 x3 = *reinterpret_cast<const float4*>(&h1p[(size_t)(n0 + 3) * C1 + k]);
        acc0 += x0.x * w0 + x0.y * w1 + x0.z * w2 + x0.w * w3;
        acc1 += x1.x * w0 + x1.y * w1 + x1.z * w2 + x1.w * w3;
        acc2 += x2.x * w0 + x2.y * w1 + x2.z * w2 + x2.w * w3;
        acc3 += x3.x * w0 + x3.y * w1 + x3.z * w2 + x3.w * w3;
    }
    const float a_s = (c < NC) ? a2s[c] : 0.f;
    const float a_d = (c < NC) ? a2d[c] : 0.f;
    float accs[4] = {acc0, acc1, acc2, acc3};
#pragma unroll
    for (int j = 0; j < 4; j++) {
        const float v = accs[j];
        if (c < NC) h2[(size_t)(n0 + j) * NC + c] = v;
        float ps = (c < NC) ? v * a_s : 0.f;
        float pd = (c < NC) ? v * a_d : 0.f;
#pragma unroll
        for (int off = 32; off >= 1; off >>= 1) {
            ps += __shfl_xor(ps, off);
            pd += __shfl_xor(pd, off);
        }
        if (lane == 0) { as2[n0 + j] = ps; ad2[n0 + j] = pd; }
    }
}

// ---- K7: layer-2 aggregation + bias + log_softmax. One wave per node.
__global__ __launch_bounds__(256) void k_agg2(
    const int* __restrict__ rowptr, const int* __restrict__ csr,
    const float* __restrict__ h2, const float* __restrict__ as2,
    const float* __restrict__ ad2, const float* __restrict__ b2,
    float* __restrict__ out)
{
    const int lane = threadIdx.x & 63;
    const int n = (blockIdx.x * blockDim.x + threadIdx.x) >> 6;
    const int c = lane;
    const int cc = (c < NC) ? c : (NC - 1);
    const float adv = ad2[n];
    const int beg = rowptr[n], end = rowptr[n + 1];
    float acc = 0.f, accw = 0.f;
    int e = beg;
    for (; e + 3 < end; e += 4) {
        const int s0 = csr[e], s1 = csr[e + 1], s2 = csr[e + 2], s3 = csr[e + 3];
        const float w0 = __expf(lrelu(as2[s0] + adv));
        const float w1 = __expf(lrelu(as2[s1] + adv));
        const float w2 = __expf(lrelu(as2[s2] + adv));
        const float w3 = __expf(lrelu(as2[s3] + adv));
        const float g0 = h2[(size_t)s0 * NC + cc];
        const float g1 = h2[(size_t)s1 * NC + cc];
        const float g2 = h2[(size_t)s2 * NC + cc];
        const float g3 = h2[(size_t)s3 * NC + cc];
        accw += (w0 + w1) + (w2 + w3);
        acc = fmaf(w0, g0, acc);
        acc = fmaf(w1, g1, acc);
        acc = fmaf(w2, g2, acc);
        acc = fmaf(w3, g3, acc);
    }
    for (; e < end; e++) {
        const int s = csr[e];
        const float w = __expf(lrelu(as2[s] + adv));
        accw += w;
        acc = fmaf(w, h2[(size_t)s * NC + cc], acc);
    }
    const float v = acc / accw + b2[cc];
    float m = (c < NC) ? v : -1e30f;
#pragma unroll
    for (int off = 32; off >= 1; off >>= 1) m = fmaxf(m, __shfl_xor(m, off));
    float S = (c < NC) ? __expf(v - m) : 0.f;
#pragma unroll
    for (int off = 32; off >= 1; off >>= 1) S += __shfl_xor(S, off);
    if (c < NC) out[(size_t)n * NC + c] = v - m - logf(S);
}

extern "C" void kernel_launch(void* const* d_in, const int* in_sizes, int n_in,
                              void* d_out, int out_size, void* d_ws, size_t ws_size,
                              hipStream_t stream)
{
    const float* x   = (const float*)d_in[0];
    const int*   ei  = (const int*)d_in[1];
    const float* W1  = (const float*)d_in[2];
    const float* a1s = (const float*)d_in[3];
    const float* a1d = (const float*)d_in[4];
    const float* b1  = (const float*)d_in[5];
    const float* W2  = (const float*)d_in[6];
    const float* a2s = (const float*)d_in[7];
    const float* a2d = (const float*)d_in[8];
    const float* b2  = (const float*)d_in[9];
    float* out = (float*)d_out;

    const int E  = in_sizes[1] / 2;   // 640000
    const int ET = E + N;             // + self loops

    char* ws = (char*)d_ws;
    float* h1  = (float*)(ws);                    // N*256 f32 = 20.48 MB
    float* h1p = (float*)(ws + 20480000);         // N*256 f32
    float* h2  = (float*)(ws + 40960000);         // N*40  f32
    float* as1 = (float*)(ws + 44160000);         // N*8
    float* ad1 = (float*)(ws + 44800000);         // N*8
    float* as2 = (float*)(ws + 45440000);         // N
    float* ad2 = (float*)(ws + 45520000);         // N
    int*   deg    = (int*)(ws + 45600000);        // N
    int*   rowptr = (int*)(ws + 45680000);        // N+1
    int*   cursor = (int*)(ws + 45760128);        // N
    int*   csr    = (int*)(ws + 45840128);        // ET ints = 2.64 MB

    hipMemsetAsync(deg, 0, N * sizeof(int), stream);

    k_gemm1<<<N / 16, 256, 0, stream>>>(x, W1, a1s, a1d, h1, as1, ad1);
    k_count<<<(ET + 255) / 256, 256, 0, stream>>>(ei, E, deg);
    k_scan<<<1, 1024, 0, stream>>>(deg, rowptr);
    k_cursor<<<(N + 255) / 256, 256, 0, stream>>>(rowptr, cursor);
    k_fill<<<(ET + 255) / 256, 256, 0, stream>>>(ei, E, cursor, csr);
    k_agg1<<<N, 256, 0, stream>>>(rowptr, csr, h1, as1, ad1, b1, h1p);
    k_gemm2<<<1250, 256, 0, stream>>>(h1p, W2, a2s, a2d, h2, as2, ad2);
    k_agg2<<<5000, 256, 0, stream>>>(rowptr, csr, h2, as2, ad2, b2, out);
}

// Round 2
// 329.850 us; speedup vs baseline: 1.2723x; 1.2723x over previous
//
#include <hip/hip_runtime.h>
#include <hip/hip_fp16.h>
#include <math.h>

#define N 20000
#define F 128
#define C1 256   // HEADS*HIDDEN
#define HEADS 8
#define HID 32
#define NC 40
#define NEG 0.2f

__device__ __forceinline__ int edge_stride(const int* ei) {
    return (ei[1] == 0 && ei[3] == 0 && ei[5] == 0 && ei[7] == 0 && ei[9] == 0) ? 2 : 1;
}

__device__ __forceinline__ float lrelu(float v) { return v > 0.f ? v : NEG * v; }

// ---- K1: h1 = x @ W1 (store fp16); as1/ad1 projections. 16 rows/block.
__global__ __launch_bounds__(256) void k_gemm1(
    const float* __restrict__ x, const float* __restrict__ W1,
    const float* __restrict__ a1s, const float* __restrict__ a1d,
    __half* __restrict__ h1h, float* __restrict__ as1, float* __restrict__ ad1)
{
    const int t = threadIdx.x;               // output column 0..255
    const int row0 = blockIdx.x * 16;
    float acc[16];
#pragma unroll
    for (int r = 0; r < 16; r++) acc[r] = 0.f;

    for (int k = 0; k < F; k += 4) {
        const float w0 = W1[(k + 0) * C1 + t];
        const float w1 = W1[(k + 1) * C1 + t];
        const float w2 = W1[(k + 2) * C1 + t];
        const float w3 = W1[(k + 3) * C1 + t];
#pragma unroll
        for (int r = 0; r < 16; r++) {
            const float4 xv = *reinterpret_cast<const float4*>(&x[(row0 + r) * F + k]);
            acc[r] = fmaf(xv.x, w0, acc[r]);
            acc[r] = fmaf(xv.y, w1, acc[r]);
            acc[r] = fmaf(xv.z, w2, acc[r]);
            acc[r] = fmaf(xv.w, w3, acc[r]);
        }
    }

    const int head = t >> 5, c = t & 31;
    const float asv = a1s[head * HID + c];
    const float adv = a1d[head * HID + c];
#pragma unroll
    for (int r = 0; r < 16; r++) {
        const float hv = acc[r];
        h1h[(size_t)(row0 + r) * C1 + t] = __float2half(hv);
        float ps = hv * asv, pd = hv * adv;
#pragma unroll
        for (int off = 16; off >= 1; off >>= 1) {
            ps += __shfl_down(ps, off, 32);
            pd += __shfl_down(pd, off, 32);
        }
        if (c == 0) {
            as1[(row0 + r) * HEADS + head] = ps;
            ad1[(row0 + r) * HEADS + head] = pd;
        }
    }
}

// ---- K2: degree count (incl. self loops)
__global__ void k_count(const int* __restrict__ ei, int E, int* __restrict__ deg)
{
    const int i = blockIdx.x * blockDim.x + threadIdx.x;
    const int ET = E + N;
    if (i >= ET) return;
    const int st = edge_stride(ei);
    const int d = (i < E) ? ei[(size_t)st * (E + i)] : (i - E);
    atomicAdd(&deg[d], 1);
}

// ---- K3: coarsened shuffle scan -> rowptr + cursor. One block, 1024 thr.
__global__ __launch_bounds__(1024) void k_scan(const int* __restrict__ deg,
                                               int* __restrict__ rowptr,
                                               int* __restrict__ cursor)
{
    __shared__ int ws[16];
    const int t = threadIdx.x;
    const int lane = t & 63, wid = t >> 6;
    int loc[20];
    const int base = t * 20;
    int run = 0;
#pragma unroll
    for (int j = 0; j < 20; j++) {
        const int i = base + j;
        const int v = (i < N) ? deg[i] : 0;
        run += v;
        loc[j] = run;     // inclusive local prefix
    }
    int v = run;
#pragma unroll
    for (int off = 1; off < 64; off <<= 1) {
        const int u = __shfl_up(v, off, 64);
        if (lane >= off) v += u;
    }
    const int excl_in_wave = v - run;
    if (lane == 63) ws[wid] = v;
    __syncthreads();
    if (t < 64) {
        int w = (lane < 16) ? ws[lane] : 0;
        const int orig = w;
#pragma unroll
        for (int off = 1; off < 16; off <<= 1) {
            const int u = __shfl_up(w, off, 64);
            if (lane >= off) w += u;
        }
        if (lane < 16) ws[lane] = w - orig;  // exclusive wave base
    }
    __syncthreads();
    const int base0 = ws[wid] + excl_in_wave;
    if (t == 0) rowptr[0] = 0;
#pragma unroll
    for (int j = 0; j < 20; j++) {
        const int i = base + j;
        if (i < N) {
            rowptr[i + 1] = base0 + loc[j];
            cursor[i] = base0 + ((j > 0) ? loc[j - 1] : 0);
        }
    }
}

// ---- K4: scatter into CSR slots + precompute layer-1 edge weights (fp16)
__global__ void k_fill(const int* __restrict__ ei, int E,
                       const float* __restrict__ as1, const float* __restrict__ ad1,
                       int* __restrict__ cursor, int* __restrict__ csr,
                       int* __restrict__ edst, __half* __restrict__ wc1)
{
    const int i = blockIdx.x * blockDim.x + threadIdx.x;
    const int ET = E + N;
    if (i >= ET) return;
    const int st = edge_stride(ei);
    int s, d;
    if (i < E) { s = ei[(size_t)st * i]; d = ei[(size_t)st * (E + i)]; }
    else       { s = i - E; d = i - E; }
    const int slot = atomicAdd(&cursor[d], 1);
    csr[slot] = s;
    edst[slot] = d;
    const float4 a0 = *reinterpret_cast<const float4*>(&as1[s * HEADS]);
    const float4 a1v = *reinterpret_cast<const float4*>(&as1[s * HEADS + 4]);
    const float4 b0 = *reinterpret_cast<const float4*>(&ad1[d * HEADS]);
    const float4 b1v = *reinterpret_cast<const float4*>(&ad1[d * HEADS + 4]);
    union { float4 f4; __half2 h2[4]; } u;
    u.h2[0] = __floats2half2_rn(__expf(lrelu(a0.x + b0.x)), __expf(lrelu(a0.y + b0.y)));
    u.h2[1] = __floats2half2_rn(__expf(lrelu(a0.z + b0.z)), __expf(lrelu(a0.w + b0.w)));
    u.h2[2] = __floats2half2_rn(__expf(lrelu(a1v.x + b1v.x)), __expf(lrelu(a1v.y + b1v.y)));
    u.h2[3] = __floats2half2_rn(__expf(lrelu(a1v.z + b1v.z)), __expf(lrelu(a1v.w + b1v.w)));
    *reinterpret_cast<float4*>(&wc1[(size_t)slot * HEADS]) = u.f4;
}

// ---- K5: layer-1 aggregation. 128 thr/node, 2 channels/thread, fp16 gather.
__global__ __launch_bounds__(128) void k_agg1(
    const int* __restrict__ rowptr, const int* __restrict__ csr,
    const __half* __restrict__ h1h, const __half* __restrict__ wc1,
    const float* __restrict__ b1, __half* __restrict__ h1p)
{
    const int n = blockIdx.x;
    const int t = threadIdx.x;            // channel pair: 2t, 2t+1
    const int head = t >> 4;
    const int beg = rowptr[n], end = rowptr[n + 1];
    float ax = 0.f, ay = 0.f, accw = 0.f;
    int e = beg;
    for (; e + 3 < end; e += 4) {
        const int s0 = csr[e], s1 = csr[e + 1], s2 = csr[e + 2], s3 = csr[e + 3];
        const float w0 = __half2float(wc1[(size_t)(e + 0) * HEADS + head]);
        const float w1 = __half2float(wc1[(size_t)(e + 1) * HEADS + head]);
        const float w2 = __half2float(wc1[(size_t)(e + 2) * HEADS + head]);
        const float w3 = __half2float(wc1[(size_t)(e + 3) * HEADS + head]);
        const float2 f0 = __half22float2(*reinterpret_cast<const __half2*>(&h1h[(size_t)s0 * C1 + 2 * t]));
        const float2 f1 = __half22float2(*reinterpret_cast<const __half2*>(&h1h[(size_t)s1 * C1 + 2 * t]));
        const float2 f2 = __half22float2(*reinterpret_cast<const __half2*>(&h1h[(size_t)s2 * C1 + 2 * t]));
        const float2 f3 = __half22float2(*reinterpret_cast<const __half2*>(&h1h[(size_t)s3 * C1 + 2 * t]));
        accw += (w0 + w1) + (w2 + w3);
        ax = fmaf(w0, f0.x, ax); ay = fmaf(w0, f0.y, ay);
        ax = fmaf(w1, f1.x, ax); ay = fmaf(w1, f1.y, ay);
        ax = fmaf(w2, f2.x, ax); ay = fmaf(w2, f2.y, ay);
        ax = fmaf(w3, f3.x, ax); ay = fmaf(w3, f3.y, ay);
    }
    for (; e < end; e++) {
        const int s = csr[e];
        const float w = __half2float(wc1[(size_t)e * HEADS + head]);
        const float2 f = __half22float2(*reinterpret_cast<const __half2*>(&h1h[(size_t)s * C1 + 2 * t]));
        accw += w;
        ax = fmaf(w, f.x, ax); ay = fmaf(w, f.y, ay);
    }
    const float inv = 1.f / accw;
    float ox = ax * inv + b1[2 * t];
    float oy = ay * inv + b1[2 * t + 1];
    ox = (ox > 0.f) ? ox : (__expf(ox) - 1.f);
    oy = (oy > 0.f) ? oy : (__expf(oy) - 1.f);
    *reinterpret_cast<__half2*>(&h1p[(size_t)n * C1 + 2 * t]) = __floats2half2_rn(ox, oy);
}

// ---- K6: h2 = h1p @ W2 (fp16 in, fp16 out) ; as2/ad2. One wave per 4 nodes.
__global__ __launch_bounds__(256) void k_gemm2(
    const __half* __restrict__ h1p, const float* __restrict__ W2,
    const float* __restrict__ a2s, const float* __restrict__ a2d,
    __half* __restrict__ h2h, float* __restrict__ as2, float* __restrict__ ad2)
{
    const int lane = threadIdx.x & 63;
    const int wid = (blockIdx.x * blockDim.x + threadIdx.x) >> 6;  // 0..4999
    const int n0 = wid * 4;
    const int c = lane;
    const int cc = (c < NC) ? c : (NC - 1);
    float acc[4] = {0.f, 0.f, 0.f, 0.f};
    for (int k = 0; k < C1; k += 8) {
        float w[8];
#pragma unroll
        for (int j = 0; j < 8; j++) w[j] = W2[(k + j) * NC + cc];
#pragma unroll
        for (int r = 0; r < 4; r++) {
            union { float4 f4; __half2 h2[4]; } u;
            u.f4 = *reinterpret_cast<const float4*>(&h1p[(size_t)(n0 + r) * C1 + k]);
#pragma unroll
            for (int j = 0; j < 4; j++) {
                const float2 f = __half22float2(u.h2[j]);
                acc[r] = fmaf(f.x, w[2 * j], acc[r]);
                acc[r] = fmaf(f.y, w[2 * j + 1], acc[r]);
            }
        }
    }
    const float a_s = (c < NC) ? a2s[c] : 0.f;
    const float a_d = (c < NC) ? a2d[c] : 0.f;
#pragma unroll
    for (int j = 0; j < 4; j++) {
        const float v = acc[j];
        if (c < NC) h2h[(size_t)(n0 + j) * NC + c] = __float2half(v);
        float ps = (c < NC) ? v * a_s : 0.f;
        float pd = (c < NC) ? v * a_d : 0.f;
#pragma unroll
        for (int off = 32; off >= 1; off >>= 1) {
            ps += __shfl_xor(ps, off);
            pd += __shfl_xor(pd, off);
        }
        if (lane == 0) { as2[n0 + j] = ps; ad2[n0 + j] = pd; }
    }
}

// ---- K6b: layer-2 edge weights in CSR order
__global__ void k_w2(const int* __restrict__ csr, const int* __restrict__ edst,
                     const float* __restrict__ as2, const float* __restrict__ ad2,
                     int ET, float* __restrict__ ws2)
{
    const int i = blockIdx.x * blockDim.x + threadIdx.x;
    if (i >= ET) return;
    ws2[i] = __expf(lrelu(as2[csr[i]] + ad2[edst[i]]));
}

// ---- K7: layer-2 aggregation + bias + log_softmax. One wave per node.
__global__ __launch_bounds__(256) void k_agg2(
    const int* __restrict__ rowptr, const int* __restrict__ csr,
    const __half* __restrict__ h2h, const float* __restrict__ ws2,
    const float* __restrict__ b2, float* __restrict__ out)
{
    const int lane = threadIdx.x & 63;
    const int n = (blockIdx.x * blockDim.x + threadIdx.x) >> 6;
    const int c = lane;
    const int cc = (c < NC) ? c : (NC - 1);
    const int beg = rowptr[n], end = rowptr[n + 1];
    float acc = 0.f, accw = 0.f;
    int e = beg;
    for (; e + 3 < end; e += 4) {
        const int s0 = csr[e], s1 = csr[e + 1], s2 = csr[e + 2], s3 = csr[e + 3];
        const float w0 = ws2[e], w1 = ws2[e + 1], w2 = ws2[e + 2], w3 = ws2[e + 3];
        const float g0 = __half2float(h2h[(size_t)s0 * NC + cc]);
        const float g1 = __half2float(h2h[(size_t)s1 * NC + cc]);
        const float g2 = __half2float(h2h[(size_t)s2 * NC + cc]);
        const float g3 = __half2float(h2h[(size_t)s3 * NC + cc]);
        accw += (w0 + w1) + (w2 + w3);
        acc = fmaf(w0, g0, acc);
        acc = fmaf(w1, g1, acc);
        acc = fmaf(w2, g2, acc);
        acc = fmaf(w3, g3, acc);
    }
    for (; e < end; e++) {
        const int s = csr[e];
        const float w = ws2[e];
        accw += w;
        acc = fmaf(w, __half2float(h2h[(size_t)s * NC + cc]), acc);
    }
    const float v = acc / accw + b2[cc];
    float m = (c < NC) ? v : -1e30f;
#pragma unroll
    for (int off = 32; off >= 1; off >>= 1) m = fmaxf(m, __shfl_xor(m, off));
    float S = (c < NC) ? __expf(v - m) : 0.f;
#pragma unroll
    for (int off = 32; off >= 1; off >>= 1) S += __shfl_xor(S, off);
    if (c < NC) out[(size_t)n * NC + c] = v - m - logf(S);
}

extern "C" void kernel_launch(void* const* d_in, const int* in_sizes, int n_in,
                              void* d_out, int out_size, void* d_ws, size_t ws_size,
                              hipStream_t stream)
{
    const float* x   = (const float*)d_in[0];
    const int*   ei  = (const int*)d_in[1];
    const float* W1  = (const float*)d_in[2];
    const float* a1s = (const float*)d_in[3];
    const float* a1d = (const float*)d_in[4];
    const float* b1  = (const float*)d_in[5];
    const float* W2  = (const float*)d_in[6];
    const float* a2s = (const float*)d_in[7];
    const float* a2d = (const float*)d_in[8];
    const float* b2  = (const float*)d_in[9];
    float* out = (float*)d_out;

    const int E  = in_sizes[1] / 2;   // 640000
    const int ET = E + N;

    auto align64 = [](size_t v) { return (v + 63) & ~(size_t)63; };
    char* ws = (char*)d_ws;
    size_t off = 0;
    __half* h1h = (__half*)(ws + off); off = align64(off + (size_t)N * C1 * 2);   // 10.24 MB
    __half* h1p = (__half*)(ws + off); off = align64(off + (size_t)N * C1 * 2);   // 10.24 MB
    __half* h2h = (__half*)(ws + off); off = align64(off + (size_t)N * NC * 2);   // 1.6 MB
    float* as1 = (float*)(ws + off); off = align64(off + (size_t)N * HEADS * 4);
    float* ad1 = (float*)(ws + off); off = align64(off + (size_t)N * HEADS * 4);
    float* as2 = (float*)(ws + off); off = align64(off + (size_t)N * 4);
    float* ad2 = (float*)(ws + off); off = align64(off + (size_t)N * 4);
    int* deg    = (int*)(ws + off); off = align64(off + (size_t)N * 4);
    int* rowptr = (int*)(ws + off); off = align64(off + (size_t)(N + 1) * 4);
    int* cursor = (int*)(ws + off); off = align64(off + (size_t)N * 4);
    int* csr    = (int*)(ws + off); off = align64(off + (size_t)ET * 4);
    int* edst   = (int*)(ws + off); off = align64(off + (size_t)ET * 4);
    float* ws2  = (float*)(ws + off); off = align64(off + (size_t)ET * 4);
    __half* wc1 = (__half*)(ws + off); off = align64(off + (size_t)ET * HEADS * 2); // 10.56 MB

    hipMemsetAsync(deg, 0, N * sizeof(int), stream);

    k_gemm1<<<N / 16, 256, 0, stream>>>(x, W1, a1s, a1d, h1h, as1, ad1);
    k_count<<<(ET + 255) / 256, 256, 0, stream>>>(ei, E, deg);
    k_scan<<<1, 1024, 0, stream>>>(deg, rowptr, cursor);
    k_fill<<<(ET + 255) / 256, 256, 0, stream>>>(ei, E, as1, ad1, cursor, csr, edst, wc1);
    k_agg1<<<N, 128, 0, stream>>>(rowptr, csr, h1h, wc1, b1, h1p);
    k_gemm2<<<1250, 256, 0, stream>>>(h1p, W2, a2s, a2d, h2h, as2, ad2);
    k_w2<<<(ET + 255) / 256, 256, 0, stream>>>(csr, edst, as2, ad2, ET, ws2);
    k_agg2<<<5000, 256, 0, stream>>>(rowptr, csr, h2h, ws2, b2, out);
}

// Round 3
// 296.255 us; speedup vs baseline: 1.4166x; 1.1134x over previous
//
#include <hip/hip_runtime.h>
#include <hip/hip_fp16.h>
#include <math.h>

#define N 20000
#define NPAD 20032
#define F 128
#define C1 256   // HEADS*HIDDEN
#define HEADS 8
#define HID 32
#define NC 40
#define NEG 0.2f

typedef _Float16 half8 __attribute__((ext_vector_type(8)));
typedef _Float16 half4v __attribute__((ext_vector_type(4)));
typedef float f32x4 __attribute__((ext_vector_type(4)));

__device__ __forceinline__ int edge_stride(const int* ei) {
    return (ei[1] == 0 && ei[3] == 0 && ei[5] == 0 && ei[7] == 0 && ei[9] == 0) ? 2 : 1;
}

__device__ __forceinline__ float lrelu(float v) { return v > 0.f ? v : NEG * v; }

// ---- P1: x fp32 -> fp16, zero-pad rows N..NPAD
__global__ void k_prep_x(const float* __restrict__ x, _Float16* __restrict__ xh)
{
    const int i = blockIdx.x * blockDim.x + threadIdx.x;
    const int idx = i * 4;
    if (idx >= NPAD * F) return;
    half4v o;
    if (idx < N * F) {
        const float4 v = *reinterpret_cast<const float4*>(&x[idx]);
        o[0] = (_Float16)v.x; o[1] = (_Float16)v.y; o[2] = (_Float16)v.z; o[3] = (_Float16)v.w;
    } else {
        o[0] = (_Float16)0.f; o[1] = (_Float16)0.f; o[2] = (_Float16)0.f; o[3] = (_Float16)0.f;
    }
    *reinterpret_cast<half4v*>(&xh[idx]) = o;
}

// ---- P2: W1 fp32 -> fp16 pre-swizzled into B-fragment layout
// slot = (kstep*16 + ntile)*64 + lane ; 8 halves: B[k0+j][n], k0=ks*32+(lane>>4)*8, n=nt*16+(lane&15)
__global__ void k_prep_w(const float* __restrict__ W1, _Float16* __restrict__ w1sw)
{
    const int slot = blockIdx.x * blockDim.x + threadIdx.x;
    if (slot >= 4096) return;
    const int lane = slot & 63;
    const int tile = slot >> 6;
    const int nt = tile & 15, ks = tile >> 4;
    const int n = nt * 16 + (lane & 15);
    const int k0 = ks * 32 + (lane >> 4) * 8;
    half8 tmp;
#pragma unroll
    for (int j = 0; j < 8; j++) tmp[j] = (_Float16)W1[(k0 + j) * C1 + n];
    *reinterpret_cast<half8*>(&w1sw[(size_t)slot * 8]) = tmp;
}

// ---- K1: h1 = x @ W1 via MFMA 16x16x32 f16. One wave = 16 rows x 256 cols.
__global__ __launch_bounds__(256) void k_gemm1_mfma(
    const _Float16* __restrict__ xh, const _Float16* __restrict__ w1sw,
    __half* __restrict__ h1h)
{
    const int lane = threadIdx.x & 63;
    const int wid = (blockIdx.x * 256 + threadIdx.x) >> 6;
    const int m0 = wid * 16;
    const int g = lane >> 4, lm = lane & 15;
    half8 a[4];
    const size_t arow = (size_t)(m0 + lm) * F;
#pragma unroll
    for (int ks = 0; ks < 4; ks++)
        a[ks] = *reinterpret_cast<const half8*>(&xh[arow + ks * 32 + g * 8]);
    const int rbase = m0 + g * 4;
#pragma unroll
    for (int nt = 0; nt < 16; nt++) {
        f32x4 acc = {0.f, 0.f, 0.f, 0.f};
#pragma unroll
        for (int ks = 0; ks < 4; ks++) {
            const half8 b = *reinterpret_cast<const half8*>(&w1sw[(size_t)((ks * 16 + nt) * 64 + lane) * 8]);
            acc = __builtin_amdgcn_mfma_f32_16x16x32_f16(a[ks], b, acc, 0, 0, 0);
        }
        const int col = nt * 16 + lm;
#pragma unroll
        for (int r = 0; r < 4; r++) {
            const int row = rbase + r;
            if (row < N) h1h[(size_t)row * C1 + col] = __float2half((float)acc[r]);
        }
    }
}

// ---- K1b: as1/ad1 projections from h1h. One wave per row.
__global__ __launch_bounds__(256) void k_proj(
    const __half* __restrict__ h1h, const float* __restrict__ a1s,
    const float* __restrict__ a1d, float* __restrict__ as1, float* __restrict__ ad1)
{
    const int lane = threadIdx.x & 63;
    const int row = (blockIdx.x * 256 + threadIdx.x) >> 6;
    const int c0 = lane * 4;
    const int head = lane >> 3;
    union { float2 f2; __half2 h2[2]; } u;
    u.f2 = *reinterpret_cast<const float2*>(&h1h[(size_t)row * C1 + c0]);
    const float2 p0 = __half22float2(u.h2[0]), p1 = __half22float2(u.h2[1]);
    const int ai = head * HID + (c0 & 31);
    float ps = p0.x * a1s[ai] + p0.y * a1s[ai + 1] + p1.x * a1s[ai + 2] + p1.y * a1s[ai + 3];
    float pd = p0.x * a1d[ai] + p0.y * a1d[ai + 1] + p1.x * a1d[ai + 2] + p1.y * a1d[ai + 3];
#pragma unroll
    for (int off = 1; off <= 4; off <<= 1) {
        ps += __shfl_xor(ps, off);
        pd += __shfl_xor(pd, off);
    }
    if ((lane & 7) == 0) {
        as1[row * HEADS + head] = ps;
        ad1[row * HEADS + head] = pd;
    }
}

// ---- K2: degree count (incl. self loops)
__global__ void k_count(const int* __restrict__ ei, int E, int* __restrict__ deg)
{
    const int i = blockIdx.x * blockDim.x + threadIdx.x;
    const int ET = E + N;
    if (i >= ET) return;
    const int st = edge_stride(ei);
    const int d = (i < E) ? ei[(size_t)st * (E + i)] : (i - E);
    atomicAdd(&deg[d], 1);
}

// ---- K3: coarsened shuffle scan -> rowptr + cursor. One block, 1024 thr.
__global__ __launch_bounds__(1024) void k_scan(const int* __restrict__ deg,
                                               int* __restrict__ rowptr,
                                               int* __restrict__ cursor)
{
    __shared__ int ws[16];
    const int t = threadIdx.x;
    const int lane = t & 63, wid = t >> 6;
    int loc[20];
    const int base = t * 20;
    int run = 0;
#pragma unroll
    for (int j = 0; j < 20; j++) {
        const int i = base + j;
        const int v = (i < N) ? deg[i] : 0;
        run += v;
        loc[j] = run;
    }
    int v = run;
#pragma unroll
    for (int off = 1; off < 64; off <<= 1) {
        const int u = __shfl_up(v, off, 64);
        if (lane >= off) v += u;
    }
    const int excl_in_wave = v - run;
    if (lane == 63) ws[wid] = v;
    __syncthreads();
    if (t < 64) {
        int w = (lane < 16) ? ws[lane] : 0;
        const int orig = w;
#pragma unroll
        for (int off = 1; off < 16; off <<= 1) {
            const int u = __shfl_up(w, off, 64);
            if (lane >= off) w += u;
        }
        if (lane < 16) ws[lane] = w - orig;
    }
    __syncthreads();
    const int base0 = ws[wid] + excl_in_wave;
    if (t == 0) rowptr[0] = 0;
#pragma unroll
    for (int j = 0; j < 20; j++) {
        const int i = base + j;
        if (i < N) {
            rowptr[i + 1] = base0 + loc[j];
            cursor[i] = base0 + ((j > 0) ? loc[j - 1] : 0);
        }
    }
}

// ---- K4: scatter into CSR slots + precompute layer-1 edge weights (fp16)
__global__ void k_fill(const int* __restrict__ ei, int E,
                       const float* __restrict__ as1, const float* __restrict__ ad1,
                       int* __restrict__ cursor, int* __restrict__ csr,
                       int* __restrict__ edst, __half* __restrict__ wc1)
{
    const int i = blockIdx.x * blockDim.x + threadIdx.x;
    const int ET = E + N;
    if (i >= ET) return;
    const int st = edge_stride(ei);
    int s, d;
    if (i < E) { s = ei[(size_t)st * i]; d = ei[(size_t)st * (E + i)]; }
    else       { s = i - E; d = i - E; }
    const int slot = atomicAdd(&cursor[d], 1);
    csr[slot] = s;
    edst[slot] = d;
    const float4 a0 = *reinterpret_cast<const float4*>(&as1[s * HEADS]);
    const float4 a1v = *reinterpret_cast<const float4*>(&as1[s * HEADS + 4]);
    const float4 b0 = *reinterpret_cast<const float4*>(&ad1[d * HEADS]);
    const float4 b1v = *reinterpret_cast<const float4*>(&ad1[d * HEADS + 4]);
    union { float4 f4; __half2 h2[4]; } u;
    u.h2[0] = __floats2half2_rn(__expf(lrelu(a0.x + b0.x)), __expf(lrelu(a0.y + b0.y)));
    u.h2[1] = __floats2half2_rn(__expf(lrelu(a0.z + b0.z)), __expf(lrelu(a0.w + b0.w)));
    u.h2[2] = __floats2half2_rn(__expf(lrelu(a1v.x + b1v.x)), __expf(lrelu(a1v.y + b1v.y)));
    u.h2[3] = __floats2half2_rn(__expf(lrelu(a1v.z + b1v.z)), __expf(lrelu(a1v.w + b1v.w)));
    *reinterpret_cast<float4*>(&wc1[(size_t)slot * HEADS]) = u.f4;
}

// ---- K5: layer-1 aggregation. 128 thr/node, 2 channels/thread, fp16 gather.
__global__ __launch_bounds__(128) void k_agg1(
    const int* __restrict__ rowptr, const int* __restrict__ csr,
    const __half* __restrict__ h1h, const __half* __restrict__ wc1,
    const float* __restrict__ b1, __half* __restrict__ h1p)
{
    const int n = blockIdx.x;
    const int t = threadIdx.x;
    const int head = t >> 4;
    const int beg = rowptr[n], end = rowptr[n + 1];
    float ax = 0.f, ay = 0.f, accw = 0.f;
    int e = beg;
    for (; e + 3 < end; e += 4) {
        const int s0 = csr[e], s1 = csr[e + 1], s2 = csr[e + 2], s3 = csr[e + 3];
        const float w0 = __half2float(wc1[(size_t)(e + 0) * HEADS + head]);
        const float w1 = __half2float(wc1[(size_t)(e + 1) * HEADS + head]);
        const float w2 = __half2float(wc1[(size_t)(e + 2) * HEADS + head]);
        const float w3 = __half2float(wc1[(size_t)(e + 3) * HEADS + head]);
        const float2 f0 = __half22float2(*reinterpret_cast<const __half2*>(&h1h[(size_t)s0 * C1 + 2 * t]));
        const float2 f1 = __half22float2(*reinterpret_cast<const __half2*>(&h1h[(size_t)s1 * C1 + 2 * t]));
        const float2 f2 = __half22float2(*reinterpret_cast<const __half2*>(&h1h[(size_t)s2 * C1 + 2 * t]));
        const float2 f3 = __half22float2(*reinterpret_cast<const __half2*>(&h1h[(size_t)s3 * C1 + 2 * t]));
        accw += (w0 + w1) + (w2 + w3);
        ax = fmaf(w0, f0.x, ax); ay = fmaf(w0, f0.y, ay);
        ax = fmaf(w1, f1.x, ax); ay = fmaf(w1, f1.y, ay);
        ax = fmaf(w2, f2.x, ax); ay = fmaf(w2, f2.y, ay);
        ax = fmaf(w3, f3.x, ax); ay = fmaf(w3, f3.y, ay);
    }
    for (; e < end; e++) {
        const int s = csr[e];
        const float w = __half2float(wc1[(size_t)e * HEADS + head]);
        const float2 f = __half22float2(*reinterpret_cast<const __half2*>(&h1h[(size_t)s * C1 + 2 * t]));
        accw += w;
        ax = fmaf(w, f.x, ax); ay = fmaf(w, f.y, ay);
    }
    const float inv = 1.f / accw;
    float ox = ax * inv + b1[2 * t];
    float oy = ay * inv + b1[2 * t + 1];
    ox = (ox > 0.f) ? ox : (__expf(ox) - 1.f);
    oy = (oy > 0.f) ? oy : (__expf(oy) - 1.f);
    *reinterpret_cast<__half2*>(&h1p[(size_t)n * C1 + 2 * t]) = __floats2half2_rn(ox, oy);
}

// ---- K6: h2 = h1p @ W2 ; as2/ad2. One wave per 4 nodes.
__global__ __launch_bounds__(256) void k_gemm2(
    const __half* __restrict__ h1p, const float* __restrict__ W2,
    const float* __restrict__ a2s, const float* __restrict__ a2d,
    __half* __restrict__ h2h, float* __restrict__ as2, float* __restrict__ ad2)
{
    const int lane = threadIdx.x & 63;
    const int wid = (blockIdx.x * blockDim.x + threadIdx.x) >> 6;
    const int n0 = wid * 4;
    const int c = lane;
    const int cc = (c < NC) ? c : (NC - 1);
    float acc[4] = {0.f, 0.f, 0.f, 0.f};
    for (int k = 0; k < C1; k += 8) {
        float w[8];
#pragma unroll
        for (int j = 0; j < 8; j++) w[j] = W2[(k + j) * NC + cc];
#pragma unroll
        for (int r = 0; r < 4; r++) {
            union { float4 f4; __half2 h2[4]; } u;
            u.f4 = *reinterpret_cast<const float4*>(&h1p[(size_t)(n0 + r) * C1 + k]);
#pragma unroll
            for (int j = 0; j < 4; j++) {
                const float2 f = __half22float2(u.h2[j]);
                acc[r] = fmaf(f.x, w[2 * j], acc[r]);
                acc[r] = fmaf(f.y, w[2 * j + 1], acc[r]);
            }
        }
    }
    const float a_s = (c < NC) ? a2s[c] : 0.f;
    const float a_d = (c < NC) ? a2d[c] : 0.f;
#pragma unroll
    for (int j = 0; j < 4; j++) {
        const float v = acc[j];
        if (c < NC) h2h[(size_t)(n0 + j) * NC + c] = __float2half(v);
        float ps = (c < NC) ? v * a_s : 0.f;
        float pd = (c < NC) ? v * a_d : 0.f;
#pragma unroll
        for (int off = 32; off >= 1; off >>= 1) {
            ps += __shfl_xor(ps, off);
            pd += __shfl_xor(pd, off);
        }
        if (lane == 0) { as2[n0 + j] = ps; ad2[n0 + j] = pd; }
    }
}

// ---- K6b: layer-2 edge weights in CSR order
__global__ void k_w2(const int* __restrict__ csr, const int* __restrict__ edst,
                     const float* __restrict__ as2, const float* __restrict__ ad2,
                     int ET, float* __restrict__ ws2)
{
    const int i = blockIdx.x * blockDim.x + threadIdx.x;
    if (i >= ET) return;
    ws2[i] = __expf(lrelu(as2[csr[i]] + ad2[edst[i]]));
}

// ---- K7: layer-2 aggregation + bias + log_softmax. One wave per node.
__global__ __launch_bounds__(256) void k_agg2(
    const int* __restrict__ rowptr, const int* __restrict__ csr,
    const __half* __restrict__ h2h, const float* __restrict__ ws2,
    const float* __restrict__ b2, float* __restrict__ out)
{
    const int lane = threadIdx.x & 63;
    const int n = (blockIdx.x * blockDim.x + threadIdx.x) >> 6;
    const int c = lane;
    const int cc = (c < NC) ? c : (NC - 1);
    const int beg = rowptr[n], end = rowptr[n + 1];
    float acc = 0.f, accw = 0.f;
    int e = beg;
    for (; e + 3 < end; e += 4) {
        const int s0 = csr[e], s1 = csr[e + 1], s2 = csr[e + 2], s3 = csr[e + 3];
        const float w0 = ws2[e], w1 = ws2[e + 1], w2 = ws2[e + 2], w3 = ws2[e + 3];
        const float g0 = __half2float(h2h[(size_t)s0 * NC + cc]);
        const float g1 = __half2float(h2h[(size_t)s1 * NC + cc]);
        const float g2 = __half2float(h2h[(size_t)s2 * NC + cc]);
        const float g3 = __half2float(h2h[(size_t)s3 * NC + cc]);
        accw += (w0 + w1) + (w2 + w3);
        acc = fmaf(w0, g0, acc);
        acc = fmaf(w1, g1, acc);
        acc = fmaf(w2, g2, acc);
        acc = fmaf(w3, g3, acc);
    }
    for (; e < end; e++) {
        const int s = csr[e];
        const float w = ws2[e];
        accw += w;
        acc = fmaf(w, __half2float(h2h[(size_t)s * NC + cc]), acc);
    }
    const float v = acc / accw + b2[cc];
    float m = (c < NC) ? v : -1e30f;
#pragma unroll
    for (int off = 32; off >= 1; off >>= 1) m = fmaxf(m, __shfl_xor(m, off));
    float S = (c < NC) ? __expf(v - m) : 0.f;
#pragma unroll
    for (int off = 32; off >= 1; off >>= 1) S += __shfl_xor(S, off);
    if (c < NC) out[(size_t)n * NC + c] = v - m - logf(S);
}

extern "C" void kernel_launch(void* const* d_in, const int* in_sizes, int n_in,
                              void* d_out, int out_size, void* d_ws, size_t ws_size,
                              hipStream_t stream)
{
    const float* x   = (const float*)d_in[0];
    const int*   ei  = (const int*)d_in[1];
    const float* W1  = (const float*)d_in[2];
    const float* a1s = (const float*)d_in[3];
    const float* a1d = (const float*)d_in[4];
    const float* b1  = (const float*)d_in[5];
    const float* W2  = (const float*)d_in[6];
    const float* a2s = (const float*)d_in[7];
    const float* a2d = (const float*)d_in[8];
    const float* b2  = (const float*)d_in[9];
    float* out = (float*)d_out;

    const int E  = in_sizes[1] / 2;
    const int ET = E + N;

    auto align64 = [](size_t v) { return (v + 63) & ~(size_t)63; };
    char* ws = (char*)d_ws;
    size_t off = 0;
    _Float16* xh  = (_Float16*)(ws + off); off = align64(off + (size_t)NPAD * F * 2);  // 5.13 MB
    _Float16* w1sw = (_Float16*)(ws + off); off = align64(off + (size_t)4096 * 8 * 2); // 64 KB
    __half* h1h = (__half*)(ws + off); off = align64(off + (size_t)N * C1 * 2);
    __half* h1p = (__half*)(ws + off); off = align64(off + (size_t)N * C1 * 2);
    __half* h2h = (__half*)(ws + off); off = align64(off + (size_t)N * NC * 2);
    float* as1 = (float*)(ws + off); off = align64(off + (size_t)N * HEADS * 4);
    float* ad1 = (float*)(ws + off); off = align64(off + (size_t)N * HEADS * 4);
    float* as2 = (float*)(ws + off); off = align64(off + (size_t)N * 4);
    float* ad2 = (float*)(ws + off); off = align64(off + (size_t)N * 4);
    int* deg    = (int*)(ws + off); off = align64(off + (size_t)N * 4);
    int* rowptr = (int*)(ws + off); off = align64(off + (size_t)(N + 1) * 4);
    int* cursor = (int*)(ws + off); off = align64(off + (size_t)N * 4);
    int* csr    = (int*)(ws + off); off = align64(off + (size_t)ET * 4);
    int* edst   = (int*)(ws + off); off = align64(off + (size_t)ET * 4);
    float* ws2  = (float*)(ws + off); off = align64(off + (size_t)ET * 4);
    __half* wc1 = (__half*)(ws + off); off = align64(off + (size_t)ET * HEADS * 2);

    hipMemsetAsync(deg, 0, N * sizeof(int), stream);

    k_prep_x<<<(NPAD * F / 4 + 255) / 256, 256, 0, stream>>>(x, xh);
    k_prep_w<<<16, 256, 0, stream>>>(W1, w1sw);
    k_gemm1_mfma<<<313, 256, 0, stream>>>(xh, w1sw, h1h);
    k_proj<<<5000, 256, 0, stream>>>(h1h, a1s, a1d, as1, ad1);
    k_count<<<(ET + 255) / 256, 256, 0, stream>>>(ei, E, deg);
    k_scan<<<1, 1024, 0, stream>>>(deg, rowptr, cursor);
    k_fill<<<(ET + 255) / 256, 256, 0, stream>>>(ei, E, as1, ad1, cursor, csr, edst, wc1);
    k_agg1<<<N, 128, 0, stream>>>(rowptr, csr, h1h, wc1, b1, h1p);
    k_gemm2<<<1250, 256, 0, stream>>>(h1p, W2, a2s, a2d, h2h, as2, ad2);
    k_w2<<<(ET + 255) / 256, 256, 0, stream>>>(csr, edst, as2, ad2, ET, ws2);
    k_agg2<<<5000, 256, 0, stream>>>(rowptr, csr, h2h, ws2, b2, out);
}